// Round 2
// baseline (149.052 us; speedup 1.0000x reference)
//
#include <hip/hip_runtime.h>
#include <hip/hip_bf16.h>

typedef __bf16 bf16_t;
typedef __bf16 bf16x8 __attribute__((ext_vector_type(8)));
typedef float f32x4 __attribute__((ext_vector_type(4)));
typedef unsigned short u16;
typedef unsigned int u32;

#define CH    128
#define NTOK  4096
#define DIMH  32

__device__ __forceinline__ float fast_exp2(float x) {
#if __has_builtin(__builtin_amdgcn_exp2f)
  return __builtin_amdgcn_exp2f(x);
#else
  return exp2f(x);
#endif
}

// ===================== Kernel A: QKV projection =====================
// x: [B][128][4096] f32, w: [384][128] f32.
// Writes: qs [bh][n][32] bf16 (pre-scaled by 1/sqrt(32)*log2e), ks same layout,
//         vs [bh][32][n] bf16.  64x64 output tile per block, K=128 in one shot.
__global__ __launch_bounds__(256)
void qkv_proj(const float* __restrict__ x, const float* __restrict__ w,
              bf16_t* __restrict__ qs, bf16_t* __restrict__ ks, bf16_t* __restrict__ vs)
{
  __shared__ float xs[128][64];
  __shared__ float wt[128][64];
  const int tid = threadIdx.x;
  const int n0 = blockIdx.x * 64;
  const int o0 = blockIdx.y * 64;
  const int b  = blockIdx.z;

  { // stage x tile [128 c][64 n] via float4 (coalesced)
    const float* xb = x + ((size_t)b * CH) * NTOK + n0;
    const int f4 = tid & 15, c0 = tid >> 4;
    #pragma unroll
    for (int p = 0; p < 8; ++p) {
      const int c = p * 16 + c0;
      *(float4*)&xs[c][f4 * 4] = *(const float4*)(xb + (size_t)c * NTOK + f4 * 4);
    }
  }
  { // stage w tile transposed: wt[c][o_local]
    const int o_l = tid & 63, q4 = tid >> 6;
    const float* wrow = w + (size_t)(o0 + o_l) * CH;
    #pragma unroll
    for (int p = 0; p < 8; ++p) {
      const int c4 = p * 4 + q4;
      const float4 v4 = *(const float4*)(wrow + c4 * 4);
      wt[c4*4+0][o_l] = v4.x;
      wt[c4*4+1][o_l] = v4.y;
      wt[c4*4+2][o_l] = v4.z;
      wt[c4*4+3][o_l] = v4.w;
    }
  }
  __syncthreads();

  const int tx = tid & 15, ty = tid >> 4;
  float acc[4][4] = {};
  for (int c = 0; c < 128; ++c) {
    const float4 xv = *(const float4*)&xs[c][tx * 4];
    const float4 wv = *(const float4*)&wt[c][ty * 4];
    const float xa[4] = {xv.x, xv.y, xv.z, xv.w};
    const float wa[4] = {wv.x, wv.y, wv.z, wv.w};
    #pragma unroll
    for (int io = 0; io < 4; ++io)
      #pragma unroll
      for (int in = 0; in < 4; ++in)
        acc[io][in] += wa[io] * xa[in];
  }
  __syncthreads();

  // stage output tile in LDS (reuse xs region) so stores can be re-mapped coalesced
  float (*out_s)[65] = (float(*)[65])&xs[0][0];
  #pragma unroll
  for (int io = 0; io < 4; ++io)
    #pragma unroll
    for (int in = 0; in < 4; ++in)
      out_s[ty*4+io][tx*4+in] = acc[io][in];
  __syncthreads();

  const float QSCALE = 0.17677669529663687f * 1.4426950408889634f; // 32^-0.5 * log2(e)
  if (o0 < 256) {
    // q or k: [bh][n][d]  (consecutive lanes -> consecutive d)
    bf16_t* dst = (o0 < 128) ? qs : ks;
    const float mul = (o0 < 128) ? QSCALE : 1.0f;
    const int obase = o0 & 127;
    #pragma unroll
    for (int p = 0; p < 16; ++p) {
      const int n_l = p * 4 + (tid >> 6);
      const int o_l = tid & 63;
      const int o = obase + o_l;
      const int h = o >> 5, d = o & 31;
      dst[(((size_t)(b*4 + h)) * NTOK + n0 + n_l) * DIMH + d] = (bf16_t)(out_s[o_l][n_l] * mul);
    }
  } else {
    // v: [bh][d][n]  (consecutive lanes -> consecutive n)
    const int obase = o0 - 256;
    #pragma unroll
    for (int p = 0; p < 16; ++p) {
      const int o_l = p * 4 + (tid >> 6);
      const int n_l = tid & 63;
      const int o = obase + o_l;
      const int h = o >> 5, d = o & 31;
      vs[(((size_t)(b*4 + h)) * DIMH + d) * NTOK + n0 + n_l] = (bf16_t)out_s[o_l][n_l];
    }
  }
}

// ===================== Kernel B: flash attention (split-j) =====================
// Swapped QK^T: S^T[j,i] = mfma(A=K_tile, B=Q_tile). Per wave: 16 i-rows.
// Online softmax per-lane-column (i = lane&15): 2 shfl_xor reductions only.
// PV computed as O^T = mfma(A=V^T, B=P) so output lands in [d][n] layout.
// K/V read from global (per head K+V = 512KB, L2-resident; bh is fastest grid
// dim -> same head lands on same XCD under round-robin dispatch).
// Split-j: blockIdx.z picks a j-range; writes unnormalized A^T + (m,l) to ws.
__global__ __launch_bounds__(256)
void attn_fwd(const bf16_t* __restrict__ qs, const bf16_t* __restrict__ ks,
              const bf16_t* __restrict__ vs, float* __restrict__ Apart,
              float* __restrict__ ml, int jb_per)
{
  __shared__ u16 p_lds[4][16][72];  // per-wave P staging, stride 72
  const int bh    = blockIdx.x;   // 0..7
  const int itile = blockIdx.y;   // 0..63
  const int split = blockIdx.z;
  const int tid   = threadIdx.x;
  const int wv   = tid >> 6;
  const int lane = tid & 63;
  const int g = lane >> 4, r = lane & 15;
  const int i_base = itile * 64 + wv * 16;

  const bf16_t* qh = qs + ((size_t)bh * NTOK) * DIMH;
  const bf16_t* kh = ks + ((size_t)bh * NTOK) * DIMH;
  const bf16_t* vh = vs + ((size_t)bh * DIMH) * NTOK;

  // Q B-frag (hoisted): col=i (lane&15), k=d ((lane>>4)*8+e)
  const bf16x8 qfrag = *(const bf16x8*)(qh + (size_t)(i_base + r) * DIMH + g * 8);

  f32x4 acc0 = {0.f,0.f,0.f,0.f}, acc1 = {0.f,0.f,0.f,0.f};
  const f32x4 zero = {0.f,0.f,0.f,0.f};
  float m_run = -INFINITY, l_run = 0.f;
  u16 (*prow)[72] = p_lds[wv];

  const int jb0 = split * jb_per;
  for (int jb = jb0; jb < jb0 + jb_per; ++jb) {
    const int j0 = jb * 64;
    // QK^T: 4 j-subtiles of 16; K A-frag: row=j (lane&15), k=d
    f32x4 st[4];
    #pragma unroll
    for (int t = 0; t < 4; ++t) {
      const bf16x8 kf = *(const bf16x8*)(kh + (size_t)(j0 + 16*t + r) * DIMH + g * 8);
      st[t] = __builtin_amdgcn_mfma_f32_16x16x32_bf16(kf, qfrag, zero, 0, 0, 0);
    }
    // lane holds S^T[j=16t+4g+u][i=i_base+r]: all 16 values belong to ONE i.
    float m = -INFINITY;
    #pragma unroll
    for (int t = 0; t < 4; ++t)
      #pragma unroll
      for (int u = 0; u < 4; ++u)
        m = fmaxf(m, st[t][u]);
    m = fmaxf(m, __shfl_xor(m, 16));
    m = fmaxf(m, __shfl_xor(m, 32));
    const float m_new = fmaxf(m_run, m);
    const float alpha = fast_exp2(m_run - m_new);

    float psum = 0.f;
    u32 pk0[4], pk1[4];
    #pragma unroll
    for (int t = 0; t < 4; ++t) {
      const float p0 = fast_exp2(st[t][0] - m_new);
      const float p1 = fast_exp2(st[t][1] - m_new);
      const float p2 = fast_exp2(st[t][2] - m_new);
      const float p3 = fast_exp2(st[t][3] - m_new);
      psum += (p0 + p1) + (p2 + p3);
      const u16 b0 = __builtin_bit_cast(u16, (__bf16)p0);
      const u16 b1 = __builtin_bit_cast(u16, (__bf16)p1);
      const u16 b2 = __builtin_bit_cast(u16, (__bf16)p2);
      const u16 b3 = __builtin_bit_cast(u16, (__bf16)p3);
      pk0[t] = ((u32)b1 << 16) | b0;   // j = 16t+4g+0, +1
      pk1[t] = ((u32)b3 << 16) | b2;   // j = 16t+4g+2, +3
    }
    psum += __shfl_xor(psum, 16);
    psum += __shfl_xor(psum, 32);
    l_run = l_run * alpha + psum;
    m_run = m_new;
    #pragma unroll
    for (int u = 0; u < 4; ++u) { acc0[u] *= alpha; acc1[u] *= alpha; }

    // P^T bounce through LDS: write [i=r][j], read B-frag [i=lane&15][j=32c+8g..+7]
    #pragma unroll
    for (int t = 0; t < 4; ++t) {
      u32* pw = (u32*)&prow[r][16*t + 4*g];
      pw[0] = pk0[t];
      pw[1] = pk1[t];
    }
    asm volatile("s_waitcnt lgkmcnt(0)" ::: "memory");  // in-wave cross-lane LDS visibility

    #pragma unroll
    for (int c = 0; c < 2; ++c) {
      const uint4 praw = *(const uint4*)&prow[r][32*c + 8*g];
      const bf16x8 pfrag = __builtin_bit_cast(bf16x8, praw);
      // V^T A-frag: row=d (lane&15), k=j; vs layout [d][n] makes this a 16B load
      const bf16_t* vb = vh + (size_t)r * NTOK + (j0 + 32*c + 8*g);
      const bf16x8 vf0 = *(const bf16x8*)(vb);
      const bf16x8 vf1 = *(const bf16x8*)(vb + (size_t)16 * NTOK);
      acc0 = __builtin_amdgcn_mfma_f32_16x16x32_bf16(vf0, pfrag, acc0, 0, 0, 0);
      acc1 = __builtin_amdgcn_mfma_f32_16x16x32_bf16(vf1, pfrag, acc1, 0, 0, 0);
    }
  }

  // A^T[d][i] store (unnormalized); lane holds rows d=dt*16+4g+u, col i=i_base+r
  float* ad = Apart + (((size_t)(split*8 + bh)) * DIMH) * NTOK + i_base + r;
  #pragma unroll
  for (int u = 0; u < 4; ++u) {
    ad[(size_t)(4*g + u) * NTOK]      = acc0[u];
    ad[(size_t)(16 + 4*g + u) * NTOK] = acc1[u];
  }
  float* mlb = ml + ((size_t)(split*8 + bh) * 2) * NTOK;
  if (g == 0) mlb[i_base + r]        = m_run;
  if (g == 1) mlb[NTOK + i_base + r] = l_run;
}

// ===================== Kernel B2: split-j combine =====================
// O^T[bh][d][i] = (sum_s w_s A_s[d][i]) / (sum_s w_s l_s),  w_s = exp2(m_s - m*)
template<int NS>
__global__ __launch_bounds__(256)
void attn_combine(const float* __restrict__ Apart, const float* __restrict__ ml,
                  float* __restrict__ ot)
{
  const int bh = blockIdx.x;
  const int i0 = blockIdx.y * 1024 + threadIdx.x * 4;
  f32x4 mv[NS], lv[NS], w[NS];
  #pragma unroll
  for (int s = 0; s < NS; ++s) {
    const float* mlb = ml + ((size_t)(s*8 + bh) * 2) * NTOK;
    mv[s] = *(const f32x4*)(mlb + i0);
    lv[s] = *(const f32x4*)(mlb + NTOK + i0);
  }
  f32x4 inv;
  #pragma unroll
  for (int c = 0; c < 4; ++c) {
    float ms = mv[0][c];
    #pragma unroll
    for (int s = 1; s < NS; ++s) ms = fmaxf(ms, mv[s][c]);
    float lt = 0.f;
    #pragma unroll
    for (int s = 0; s < NS; ++s) {
      const float ww = fast_exp2(mv[s][c] - ms);
      w[s][c] = ww;
      lt += ww * lv[s][c];
    }
    inv[c] = 1.0f / lt;
  }
  #pragma unroll 4
  for (int d = 0; d < 32; ++d) {
    f32x4 acc = {0.f,0.f,0.f,0.f};
    #pragma unroll
    for (int s = 0; s < NS; ++s) {
      const f32x4 a = *(const f32x4*)(Apart + (((size_t)(s*8 + bh)) * DIMH + d) * NTOK + i0);
      acc += w[s] * a;
    }
    acc *= inv;
    *(f32x4*)(ot + ((size_t)bh * DIMH + d) * NTOK + i0) = acc;
  }
}

// ===================== Kernel C: output projection + bias =====================
// ain: [b][128=h*32+d][4096] f32 (== attn O^T layout), w: [128][128], out: [b][128][4096]
__global__ __launch_bounds__(256)
void out_proj(const float* __restrict__ ain, const float* __restrict__ w,
              const float* __restrict__ bias, float* __restrict__ out)
{
  __shared__ float xs[128][64];
  __shared__ float wt[128][64];
  const int tid = threadIdx.x;
  const int n0 = blockIdx.x * 64;
  const int o0 = blockIdx.y * 64;
  const int b  = blockIdx.z;

  {
    const float* xb = ain + ((size_t)b * CH) * NTOK + n0;
    const int f4 = tid & 15, c0 = tid >> 4;
    #pragma unroll
    for (int p = 0; p < 8; ++p) {
      const int c = p * 16 + c0;
      *(float4*)&xs[c][f4*4] = *(const float4*)(xb + (size_t)c * NTOK + f4 * 4);
    }
  }
  {
    const int o_l = tid & 63, q4 = tid >> 6;
    const float* wrow = w + (size_t)(o0 + o_l) * CH;
    #pragma unroll
    for (int p = 0; p < 8; ++p) {
      const int c4 = p * 4 + q4;
      const float4 v4 = *(const float4*)(wrow + c4 * 4);
      wt[c4*4+0][o_l] = v4.x;
      wt[c4*4+1][o_l] = v4.y;
      wt[c4*4+2][o_l] = v4.z;
      wt[c4*4+3][o_l] = v4.w;
    }
  }
  __syncthreads();

  const int tx = tid & 15, ty = tid >> 4;
  float acc[4][4] = {};
  for (int c = 0; c < 128; ++c) {
    const float4 xv = *(const float4*)&xs[c][tx*4];
    const float4 wv = *(const float4*)&wt[c][ty*4];
    const float xa[4] = {xv.x, xv.y, xv.z, xv.w};
    const float wa[4] = {wv.x, wv.y, wv.z, wv.w};
    #pragma unroll
    for (int io = 0; io < 4; ++io)
      #pragma unroll
      for (int in = 0; in < 4; ++in)
        acc[io][in] += wa[io] * xa[in];
  }

  #pragma unroll
  for (int io = 0; io < 4; ++io) {
    const int o = o0 + ty*4 + io;
    const float bv = bias[o];
    float4 res = {acc[io][0]+bv, acc[io][1]+bv, acc[io][2]+bv, acc[io][3]+bv};
    *(float4*)(out + ((size_t)b * CH + o) * NTOK + n0 + tx*4) = res;
  }
}

extern "C" void kernel_launch(void* const* d_in, const int* in_sizes, int n_in,
                              void* d_out, int out_size, void* d_ws, size_t ws_size,
                              hipStream_t stream)
{
  const float* x     = (const float*)d_in[0];
  const float* w_qkv = (const float*)d_in[1];
  const float* w_out = (const float*)d_in[2];
  const float* b_out = (const float*)d_in[3];
  float* out = (float*)d_out;

  const size_t MB = 1024 * 1024;
  // pick split count by available workspace: need 6MB (qkv) + nsplit*4.25MB
  int nsplit = 1;
  if      (ws_size >= 6*MB + 4*(4*MB + 256*1024)) nsplit = 4;
  else if (ws_size >= 6*MB + 2*(4*MB + 256*1024)) nsplit = 2;

  // layout: qs@0 (2MB), ks@2MB (2MB), vs@4MB (2MB), Apart@6MB (n*4MB),
  //         ml@6MB+n*4MB (n*256KB), ot overlays @0 (4MB; qs/ks dead by then)
  char* ws = (char*)d_ws;
  bf16_t* qs    = (bf16_t*)(ws);
  bf16_t* ks    = (bf16_t*)(ws + 2*MB);
  bf16_t* vs    = (bf16_t*)(ws + 4*MB);
  float*  Apart = (float*) (ws + 6*MB);
  float*  ml    = (float*) (ws + 6*MB + (size_t)nsplit*4*MB);
  float*  ot    = (float*) (ws);       // overlay on qs+ks

  qkv_proj<<<dim3(64, 6, 2), 256, 0, stream>>>(x, w_qkv, qs, ks, vs);
  attn_fwd<<<dim3(8, 64, nsplit), 256, 0, stream>>>(qs, ks, vs, Apart, ml, 64/nsplit);
  if      (nsplit == 4) attn_combine<4><<<dim3(8, 4), 256, 0, stream>>>(Apart, ml, ot);
  else if (nsplit == 2) attn_combine<2><<<dim3(8, 4), 256, 0, stream>>>(Apart, ml, ot);
  else                  attn_combine<1><<<dim3(8, 4), 256, 0, stream>>>(Apart, ml, ot);
  out_proj<<<dim3(64, 2, 2), 256, 0, stream>>>(ot, w_out, b_out, out);
}

// Round 3
// 126.316 us; speedup vs baseline: 1.1800x; 1.1800x over previous
//
#include <hip/hip_runtime.h>
#include <hip/hip_bf16.h>

typedef __bf16 bf16_t;
typedef __bf16 bf16x8 __attribute__((ext_vector_type(8)));
typedef float f32x4 __attribute__((ext_vector_type(4)));
typedef unsigned short u16;
typedef unsigned int u32;

#define CH    128
#define NTOK  4096
#define DIMH  32

__device__ __forceinline__ float fast_exp2(float x) {
#if __has_builtin(__builtin_amdgcn_exp2f)
  return __builtin_amdgcn_exp2f(x);
#else
  return exp2f(x);
#endif
}

// ===================== Kernel A: QKV projection =====================
// x: [B][128][4096] f32, w: [384][128] f32.
// Writes: qs [bh][n][32] bf16 (pre-scaled by 1/sqrt(32)*log2e), ks same layout,
//         vs TILED [bh][jb=64][32 d][64 j] bf16 (4KB contiguous per j-tile so
//         attention's V-frag load is a dense 2KB span, not an 8KB-stride gather).
__global__ __launch_bounds__(256)
void qkv_proj(const float* __restrict__ x, const float* __restrict__ w,
              bf16_t* __restrict__ qs, bf16_t* __restrict__ ks, bf16_t* __restrict__ vs)
{
  __shared__ float xs[128][64];
  __shared__ float wt[128][64];
  const int tid = threadIdx.x;
  const int n0 = blockIdx.x * 64;
  const int o0 = blockIdx.y * 64;
  const int b  = blockIdx.z;

  { // stage x tile [128 c][64 n] via float4 (coalesced)
    const float* xb = x + ((size_t)b * CH) * NTOK + n0;
    const int f4 = tid & 15, c0 = tid >> 4;
    #pragma unroll
    for (int p = 0; p < 8; ++p) {
      const int c = p * 16 + c0;
      *(float4*)&xs[c][f4 * 4] = *(const float4*)(xb + (size_t)c * NTOK + f4 * 4);
    }
  }
  { // stage w tile transposed: wt[c][o_local]
    const int o_l = tid & 63, q4 = tid >> 6;
    const float* wrow = w + (size_t)(o0 + o_l) * CH;
    #pragma unroll
    for (int p = 0; p < 8; ++p) {
      const int c4 = p * 4 + q4;
      const float4 v4 = *(const float4*)(wrow + c4 * 4);
      wt[c4*4+0][o_l] = v4.x;
      wt[c4*4+1][o_l] = v4.y;
      wt[c4*4+2][o_l] = v4.z;
      wt[c4*4+3][o_l] = v4.w;
    }
  }
  __syncthreads();

  const int tx = tid & 15, ty = tid >> 4;
  float acc[4][4] = {};
  for (int c = 0; c < 128; ++c) {
    const float4 xv = *(const float4*)&xs[c][tx * 4];
    const float4 wv = *(const float4*)&wt[c][ty * 4];
    const float xa[4] = {xv.x, xv.y, xv.z, xv.w};
    const float wa[4] = {wv.x, wv.y, wv.z, wv.w};
    #pragma unroll
    for (int io = 0; io < 4; ++io)
      #pragma unroll
      for (int in = 0; in < 4; ++in)
        acc[io][in] += wa[io] * xa[in];
  }
  __syncthreads();

  // stage output tile in LDS (reuse xs region) so stores can be re-mapped coalesced
  float (*out_s)[65] = (float(*)[65])&xs[0][0];
  #pragma unroll
  for (int io = 0; io < 4; ++io)
    #pragma unroll
    for (int in = 0; in < 4; ++in)
      out_s[ty*4+io][tx*4+in] = acc[io][in];
  __syncthreads();

  const float QSCALE = 0.17677669529663687f * 1.4426950408889634f; // 32^-0.5 * log2(e)
  if (o0 < 256) {
    // q or k: [bh][n][d]  (consecutive lanes -> consecutive d)
    bf16_t* dst = (o0 < 128) ? qs : ks;
    const float mul = (o0 < 128) ? QSCALE : 1.0f;
    const int obase = o0 & 127;
    #pragma unroll
    for (int p = 0; p < 16; ++p) {
      const int n_l = p * 4 + (tid >> 6);
      const int o_l = tid & 63;
      const int o = obase + o_l;
      const int h = o >> 5, d = o & 31;
      dst[(((size_t)(b*4 + h)) * NTOK + n0 + n_l) * DIMH + d] = (bf16_t)(out_s[o_l][n_l] * mul);
    }
  } else {
    // v TILED: [bh][jb][32][64]; jb = n0/64 (fixed per block), col = n&63
    const int obase = o0 - 256;
    const int jb = n0 >> 6;
    #pragma unroll
    for (int p = 0; p < 16; ++p) {
      const int o_l = p * 4 + (tid >> 6);
      const int n_l = tid & 63;   // col, consecutive lanes -> contiguous 128B
      const int o = obase + o_l;
      const int h = o >> 5, d = o & 31;
      vs[(((size_t)(b*4 + h) * 64 + jb) * DIMH + d) * 64 + n_l] = (bf16_t)out_s[o_l][n_l];
    }
  }
}

// ===================== Kernel B: flash attention (split-j, pipelined) =====================
// Swapped QK^T: S^T[j,i] = mfma(A=K_tile, B=Q_tile). Per wave: 16 i-rows.
// Online softmax per-lane-column (i = lane&15) with defer-max (T13, THR=8 log2).
// PV as O^T = mfma(A=V^T, B=P); V read from tiled layout (dense 2KB frag span).
// K/V frags for jb+1 are loaded BEFORE the softmax/LDS-clobber of jb so their
// L2 latency hides under ~1500cy of compute (register double-buffer).
__global__ __launch_bounds__(256)
void attn_fwd(const bf16_t* __restrict__ qs, const bf16_t* __restrict__ ks,
              const bf16_t* __restrict__ vs, float* __restrict__ Apart,
              float* __restrict__ ml, int jb_per)
{
  __shared__ u16 p_lds[4][16][72];  // per-wave P staging, stride 72
  const int bh    = blockIdx.x;   // 0..7 (fastest dim -> one head per XCD)
  const int itile = blockIdx.y;
  const int split = blockIdx.z;
  const int tid   = threadIdx.x;
  const int wv   = tid >> 6;
  const int lane = tid & 63;
  const int g = lane >> 4, r = lane & 15;
  const int i_base = itile * 64 + wv * 16;

  const bf16_t* qh = qs + ((size_t)bh * NTOK) * DIMH;
  const bf16_t* kh = ks + ((size_t)bh * NTOK) * DIMH;
  const bf16_t* vh = vs + ((size_t)bh * NTOK) * DIMH;  // tiled [jb][32][64]

  // Q B-frag (hoisted): col=i (lane&15), k=d ((lane>>4)*8+e)
  const bf16x8 qfrag = *(const bf16x8*)(qh + (size_t)(i_base + r) * DIMH + g * 8);

  f32x4 acc0 = {0.f,0.f,0.f,0.f}, acc1 = {0.f,0.f,0.f,0.f};
  const f32x4 zero = {0.f,0.f,0.f,0.f};
  float m_run = -3.0e38f, l_run = 0.f;
  u16 (*prow)[72] = p_lds[wv];

  const int jb0 = split * jb_per, jb_end = jb0 + jb_per;

  // ---- prologue: load frags for jb0 ----
  // K A-frag t: row j=j0+16t+r, k=d=8g..8g+7  (dense 1KB span)
  // V A-frag:  vlo[c]: row d=r,    k=j=32c+8g..+7
  //            vhi[c]: row d=16+r  (dense 2KB span within 4KB tile)
  bf16x8 kf[4], vlo[2], vhi[2];
  {
    const bf16_t* kb = kh + (size_t)(jb0 * 64 + r) * DIMH + g * 8;
    #pragma unroll
    for (int t = 0; t < 4; ++t) kf[t] = *(const bf16x8*)(kb + t * 16 * DIMH);
    const bf16_t* vt = vh + (size_t)jb0 * (DIMH * 64) + (size_t)r * 64 + g * 8;
    #pragma unroll
    for (int c = 0; c < 2; ++c) {
      vlo[c] = *(const bf16x8*)(vt + 32 * c);
      vhi[c] = *(const bf16x8*)(vt + 16 * 64 + 32 * c);
    }
  }

  for (int jb = jb0; jb < jb_end; ++jb) {
    // ---- QK^T with current K frags ----
    f32x4 st[4];
    #pragma unroll
    for (int t = 0; t < 4; ++t)
      st[t] = __builtin_amdgcn_mfma_f32_16x16x32_bf16(kf[t], qfrag, zero, 0, 0, 0);

    // ---- issue next-tile loads NOW (before the LDS clobber) ----
    const int jn = (jb + 1 < jb_end) ? jb + 1 : jb0;
    bf16x8 kn[4], vnlo[2], vnhi[2];
    {
      const bf16_t* kb = kh + (size_t)(jn * 64 + r) * DIMH + g * 8;
      #pragma unroll
      for (int t = 0; t < 4; ++t) kn[t] = *(const bf16x8*)(kb + t * 16 * DIMH);
      const bf16_t* vt = vh + (size_t)jn * (DIMH * 64) + (size_t)r * 64 + g * 8;
      #pragma unroll
      for (int c = 0; c < 2; ++c) {
        vnlo[c] = *(const bf16x8*)(vt + 32 * c);
        vnhi[c] = *(const bf16x8*)(vt + 16 * 64 + 32 * c);
      }
    }

    // ---- online softmax (lane holds 16 S^T values for ONE i) ----
    float m = -3.0e38f;
    #pragma unroll
    for (int t = 0; t < 4; ++t) {
      const float a = fmaxf(st[t][0], st[t][1]);
      const float b = fmaxf(st[t][2], st[t][3]);
      m = fmaxf(m, fmaxf(a, b));
    }
    m = fmaxf(m, __shfl_xor(m, 16));
    m = fmaxf(m, __shfl_xor(m, 32));

    // defer-max: skip rescale while tile max hasn't outgrown running max by >8
    const bool skip = __all(m - m_run <= 8.0f);
    float m_new, alpha;
    if (skip) { m_new = m_run; alpha = 1.0f; }
    else      { m_new = fmaxf(m_run, m); alpha = fast_exp2(m_run - m_new); }

    float psum = 0.f;
    u32 pk0[4], pk1[4];
    #pragma unroll
    for (int t = 0; t < 4; ++t) {
      const float p0 = fast_exp2(st[t][0] - m_new);
      const float p1 = fast_exp2(st[t][1] - m_new);
      const float p2 = fast_exp2(st[t][2] - m_new);
      const float p3 = fast_exp2(st[t][3] - m_new);
      psum += (p0 + p1) + (p2 + p3);
      const u16 b0 = __builtin_bit_cast(u16, (__bf16)p0);
      const u16 b1 = __builtin_bit_cast(u16, (__bf16)p1);
      const u16 b2 = __builtin_bit_cast(u16, (__bf16)p2);
      const u16 b3 = __builtin_bit_cast(u16, (__bf16)p3);
      pk0[t] = ((u32)b1 << 16) | b0;   // j = 16t+4g+0, +1
      pk1[t] = ((u32)b3 << 16) | b2;   // j = 16t+4g+2, +3
    }
    psum += __shfl_xor(psum, 16);
    psum += __shfl_xor(psum, 32);
    if (skip) {
      l_run += psum;
    } else {
      l_run = l_run * alpha + psum;
      m_run = m_new;
      #pragma unroll
      for (int u = 0; u < 4; ++u) { acc0[u] *= alpha; acc1[u] *= alpha; }
    }

    // ---- P^T bounce through LDS: write [i=r][j], read B-frag [i][j=32c+8g..+7] ----
    #pragma unroll
    for (int t = 0; t < 4; ++t) {
      u32* pw = (u32*)&prow[r][16*t + 4*g];
      pw[0] = pk0[t];
      pw[1] = pk1[t];
    }
    asm volatile("s_waitcnt lgkmcnt(0)" ::: "memory");  // in-wave cross-lane LDS visibility

    #pragma unroll
    for (int c = 0; c < 2; ++c) {
      const uint4 praw = *(const uint4*)&prow[r][32*c + 8*g];
      const bf16x8 pfrag = __builtin_bit_cast(bf16x8, praw);
      acc0 = __builtin_amdgcn_mfma_f32_16x16x32_bf16(vlo[c], pfrag, acc0, 0, 0, 0);
      acc1 = __builtin_amdgcn_mfma_f32_16x16x32_bf16(vhi[c], pfrag, acc1, 0, 0, 0);
    }

    // ---- rotate double-buffer ----
    #pragma unroll
    for (int t = 0; t < 4; ++t) kf[t] = kn[t];
    #pragma unroll
    for (int c = 0; c < 2; ++c) { vlo[c] = vnlo[c]; vhi[c] = vnhi[c]; }
  }

  // A^T[d][i] store (unnormalized); lane holds rows d=4g+u (+16), col i=i_base+r
  float* ad = Apart + (((size_t)(split*8 + bh)) * DIMH) * NTOK + i_base + r;
  #pragma unroll
  for (int u = 0; u < 4; ++u) {
    ad[(size_t)(4*g + u) * NTOK]      = acc0[u];
    ad[(size_t)(16 + 4*g + u) * NTOK] = acc1[u];
  }
  float* mlb = ml + ((size_t)(split*8 + bh) * 2) * NTOK;
  if (g == 0) mlb[i_base + r]        = m_run;
  if (g == 1) mlb[NTOK + i_base + r] = l_run;
}

// ===================== Kernel B2: split-j combine =====================
// O^T[bh][d][i] = (sum_s w_s A_s[d][i]) / (sum_s w_s l_s),  w_s = exp2(m_s - m*)
template<int NS>
__global__ __launch_bounds__(256)
void attn_combine(const float* __restrict__ Apart, const float* __restrict__ ml,
                  float* __restrict__ ot)
{
  const int bh = blockIdx.x;
  const int i0 = blockIdx.y * 1024 + threadIdx.x * 4;
  f32x4 mv[NS], lv[NS], w[NS];
  #pragma unroll
  for (int s = 0; s < NS; ++s) {
    const float* mlb = ml + ((size_t)(s*8 + bh) * 2) * NTOK;
    mv[s] = *(const f32x4*)(mlb + i0);
    lv[s] = *(const f32x4*)(mlb + NTOK + i0);
  }
  f32x4 inv;
  #pragma unroll
  for (int c = 0; c < 4; ++c) {
    float ms = mv[0][c];
    #pragma unroll
    for (int s = 1; s < NS; ++s) ms = fmaxf(ms, mv[s][c]);
    float lt = 0.f;
    #pragma unroll
    for (int s = 0; s < NS; ++s) {
      const float ww = fast_exp2(mv[s][c] - ms);
      w[s][c] = ww;
      lt += ww * lv[s][c];
    }
    inv[c] = 1.0f / lt;
  }
  #pragma unroll 4
  for (int d = 0; d < 32; ++d) {
    f32x4 acc = {0.f,0.f,0.f,0.f};
    #pragma unroll
    for (int s = 0; s < NS; ++s) {
      const f32x4 a = *(const f32x4*)(Apart + (((size_t)(s*8 + bh)) * DIMH + d) * NTOK + i0);
      acc += w[s] * a;
    }
    acc *= inv;
    *(f32x4*)(ot + ((size_t)bh * DIMH + d) * NTOK + i0) = acc;
  }
}

// ===================== Kernel C: output projection + bias =====================
// ain: [b][128=h*32+d][4096] f32 (== attn O^T layout), w: [128][128], out: [b][128][4096]
__global__ __launch_bounds__(256)
void out_proj(const float* __restrict__ ain, const float* __restrict__ w,
              const float* __restrict__ bias, float* __restrict__ out)
{
  __shared__ float xs[128][64];
  __shared__ float wt[128][64];
  const int tid = threadIdx.x;
  const int n0 = blockIdx.x * 64;
  const int o0 = blockIdx.y * 64;
  const int b  = blockIdx.z;

  {
    const float* xb = ain + ((size_t)b * CH) * NTOK + n0;
    const int f4 = tid & 15, c0 = tid >> 4;
    #pragma unroll
    for (int p = 0; p < 8; ++p) {
      const int c = p * 16 + c0;
      *(float4*)&xs[c][f4*4] = *(const float4*)(xb + (size_t)c * NTOK + f4 * 4);
    }
  }
  {
    const int o_l = tid & 63, q4 = tid >> 6;
    const float* wrow = w + (size_t)(o0 + o_l) * CH;
    #pragma unroll
    for (int p = 0; p < 8; ++p) {
      const int c4 = p * 4 + q4;
      const float4 v4 = *(const float4*)(wrow + c4 * 4);
      wt[c4*4+0][o_l] = v4.x;
      wt[c4*4+1][o_l] = v4.y;
      wt[c4*4+2][o_l] = v4.z;
      wt[c4*4+3][o_l] = v4.w;
    }
  }
  __syncthreads();

  const int tx = tid & 15, ty = tid >> 4;
  float acc[4][4] = {};
  for (int c = 0; c < 128; ++c) {
    const float4 xv = *(const float4*)&xs[c][tx*4];
    const float4 wv = *(const float4*)&wt[c][ty*4];
    const float xa[4] = {xv.x, xv.y, xv.z, xv.w};
    const float wa[4] = {wv.x, wv.y, wv.z, wv.w};
    #pragma unroll
    for (int io = 0; io < 4; ++io)
      #pragma unroll
      for (int in = 0; in < 4; ++in)
        acc[io][in] += wa[io] * xa[in];
  }

  #pragma unroll
  for (int io = 0; io < 4; ++io) {
    const int o = o0 + ty*4 + io;
    const float bv = bias[o];
    float4 res = {acc[io][0]+bv, acc[io][1]+bv, acc[io][2]+bv, acc[io][3]+bv};
    *(float4*)(out + ((size_t)b * CH + o) * NTOK + n0 + tx*4) = res;
  }
}

extern "C" void kernel_launch(void* const* d_in, const int* in_sizes, int n_in,
                              void* d_out, int out_size, void* d_ws, size_t ws_size,
                              hipStream_t stream)
{
  const float* x     = (const float*)d_in[0];
  const float* w_qkv = (const float*)d_in[1];
  const float* w_out = (const float*)d_in[2];
  const float* b_out = (const float*)d_in[3];
  float* out = (float*)d_out;

  const size_t MB = 1024 * 1024;
  // pick split count by available workspace: need 6MB (qkv) + nsplit*4.25MB
  int nsplit = 1;
  if (ws_size >= 6*MB + 2*(4*MB + 256*1024)) nsplit = 2;

  // layout: qs@0 (2MB), ks@2MB (2MB), vs@4MB (2MB), Apart@6MB (n*4MB),
  //         ml@6MB+n*4MB (n*256KB), ot overlays @0 (4MB; qs/ks dead by then)
  char* ws = (char*)d_ws;
  bf16_t* qs    = (bf16_t*)(ws);
  bf16_t* ks    = (bf16_t*)(ws + 2*MB);
  bf16_t* vs    = (bf16_t*)(ws + 4*MB);
  float*  Apart = (float*) (ws + 6*MB);
  float*  ml    = (float*) (ws + 6*MB + (size_t)nsplit*4*MB);
  float*  ot    = (float*) (ws);       // overlay on qs+ks

  qkv_proj<<<dim3(64, 6, 2), 256, 0, stream>>>(x, w_qkv, qs, ks, vs);
  attn_fwd<<<dim3(8, 64, nsplit), 256, 0, stream>>>(qs, ks, vs, Apart, ml, 64/nsplit);
  if (nsplit == 2) attn_combine<2><<<dim3(8, 4), 256, 0, stream>>>(Apart, ml, ot);
  else             attn_combine<1><<<dim3(8, 4), 256, 0, stream>>>(Apart, ml, ot);
  out_proj<<<dim3(64, 2, 2), 256, 0, stream>>>(ot, w_out, b_out, out);
}